// Round 4
// baseline (1814.785 us; speedup 1.0000x reference)
//
#include <hip/hip_runtime.h>
#include <hip/hip_bf16.h>
#include <math.h>

#define D 128
#define NND 50000
#define NE 800000
#define TN 16          // nodes per block (precompute / node kernels)
#define NB1 196        // scan blocks: 196*256 = 50176 >= 50000

typedef __attribute__((ext_vector_type(8))) short shortx8;
typedef __attribute__((ext_vector_type(4))) float floatx4;

__device__ __forceinline__ float silu_f(float v) {
    return v / (1.0f + __expf(-v));
}
__device__ __forceinline__ unsigned short f2bf(float f) {
    union { float f; unsigned int u; } v; v.f = f;
    unsigned int u = v.u;
    u += 0x7fffu + ((u >> 16) & 1u);   // RNE
    return (unsigned short)(u >> 16);
}
__device__ __forceinline__ void unpk(unsigned int u, float& lo, float& hi) {
    union { unsigned int x; float f; } a, b;
    a.x = u << 16;
    b.x = u & 0xffff0000u;
    lo = a.f; hi = b.f;
}

// ---------------- zero (deg) ----------------
__global__ void zero_kernel(float4* __restrict__ p, int n4) {
    int i = blockIdx.x * blockDim.x + threadIdx.x;
    float4 z = make_float4(0.f, 0.f, 0.f, 0.f);
    for (; i < n4; i += gridDim.x * blockDim.x) p[i] = z;
}

// ---------------- CSR build ----------------
__global__ void hist_kernel(const int* __restrict__ ei, int* __restrict__ deg) {
    int e = blockIdx.x * 256 + threadIdx.x;     // NE = 3125*256 exactly
    atomicAdd(&deg[ei[e]], 1);
}

__global__ void scan1_kernel(const int* __restrict__ deg,
                             int* __restrict__ part, int* __restrict__ bsum) {
    __shared__ int s[256];
    const int tid = threadIdx.x;
    const int i = blockIdx.x * 256 + tid;
    int v = (i < NND) ? deg[i] : 0;
    s[tid] = v;
    __syncthreads();
    #pragma unroll
    for (int off = 1; off < 256; off <<= 1) {
        int t = (tid >= off) ? s[tid - off] : 0;
        __syncthreads();
        s[tid] += t;
        __syncthreads();
    }
    part[i] = s[tid] - v;                        // exclusive
    if (tid == 255) bsum[blockIdx.x] = s[255];
}

__global__ void scan2_kernel(const int* __restrict__ bsum, int* __restrict__ boff) {
    __shared__ int s[256];
    const int tid = threadIdx.x;
    int v = (tid < NB1) ? bsum[tid] : 0;
    s[tid] = v;
    __syncthreads();
    #pragma unroll
    for (int off = 1; off < 256; off <<= 1) {
        int t = (tid >= off) ? s[tid - off] : 0;
        __syncthreads();
        s[tid] += t;
        __syncthreads();
    }
    if (tid < NB1) boff[tid] = s[tid] - v;       // exclusive
}

__global__ void scan3_kernel(const int* __restrict__ part, const int* __restrict__ boff,
                             int* __restrict__ rowptr, int* __restrict__ cursor) {
    int i = blockIdx.x * 256 + threadIdx.x;
    if (i < NND) {
        int v = part[i] + boff[i >> 8];
        rowptr[i] = v;
        cursor[i] = v;
    } else if (i == NND) {
        rowptr[NND] = NE;
    }
}

// scatter col + dist2 into CSR order
__global__ void scatter_kernel(const int* __restrict__ ei, const float* __restrict__ pos,
                               int* __restrict__ cursor,
                               int* __restrict__ ecol, float* __restrict__ ed2) {
    int e = blockIdx.x * 256 + threadIdx.x;     // NE exact multiple of 256
    int r = ei[e], c = ei[NE + e];
    float dx = pos[r * 3 + 0] - pos[c * 3 + 0];
    float dy = pos[r * 3 + 1] - pos[c * 3 + 1];
    float dz = pos[r * 3 + 2] - pos[c * 3 + 2];
    int slot = atomicAdd(&cursor[r], 1);
    ecol[slot] = c;
    ed2[slot] = dx * dx + dy * dy + dz * dz;
}

// ---------------- W2f: MFMA B-fragment swizzle of W2e ----------------
__global__ void w2f_kernel(const float* __restrict__ W2e,
                           unsigned short* __restrict__ W2f) {
    int f = blockIdx.x * 256 + threadIdx.x;   // 16384 total
    int j    = f & 7;
    int mrow = (f >> 3) & 15;
    int n    = (f >> 7) & 7;
    int quad = (f >> 10) & 3;
    int s    = f >> 12;
    int col = n * 16 + mrow;
    int k   = s * 32 + quad * 8 + j;
    W2f[f] = f2bf(W2e[k * D + col]);
}

// ---------------- A = bf16(x @ W1e[0:128]), B = bf16(x @ W1e[128:256]) ----------------
__global__ void precompute_kernel(const float* __restrict__ x,
                                  const float* __restrict__ W1e,
                                  unsigned short* __restrict__ A,
                                  unsigned short* __restrict__ Bm) {
    __shared__ float xs[TN][D];
    const int j = threadIdx.x;            // 0..127
    const int n0 = blockIdx.x * TN;

    #pragma unroll
    for (int i = 0; i < TN; ++i) {
        int n = n0 + i;
        xs[i][j] = (n < NND) ? x[n * D + j] : 0.f;
    }
    __syncthreads();

    float accA[TN], accB[TN];
    #pragma unroll
    for (int i = 0; i < TN; ++i) { accA[i] = 0.f; accB[i] = 0.f; }

    for (int k4 = 0; k4 < D / 4; ++k4) {
        const int k = 4 * k4;
        float wa0 = W1e[(k + 0) * D + j];
        float wa1 = W1e[(k + 1) * D + j];
        float wa2 = W1e[(k + 2) * D + j];
        float wa3 = W1e[(k + 3) * D + j];
        float wb0 = W1e[(D + k + 0) * D + j];
        float wb1 = W1e[(D + k + 1) * D + j];
        float wb2 = W1e[(D + k + 2) * D + j];
        float wb3 = W1e[(D + k + 3) * D + j];
        #pragma unroll
        for (int i = 0; i < TN; ++i) {
            float4 v = ((const float4*)xs[i])[k4];
            accA[i] = fmaf(v.x, wa0, accA[i]);
            accA[i] = fmaf(v.y, wa1, accA[i]);
            accA[i] = fmaf(v.z, wa2, accA[i]);
            accA[i] = fmaf(v.w, wa3, accA[i]);
            accB[i] = fmaf(v.x, wb0, accB[i]);
            accB[i] = fmaf(v.y, wb1, accB[i]);
            accB[i] = fmaf(v.z, wb2, accB[i]);
            accB[i] = fmaf(v.w, wb3, accB[i]);
        }
    }
    #pragma unroll
    for (int i = 0; i < TN; ++i) {
        int n = n0 + i;
        if (n < NND) {
            A[n * D + j]  = f2bf(accA[i]);
            Bm[n * D + j] = f2bf(accB[i]);
        }
    }
}

// ---------------- fused edge MLP + per-node aggregation (no fp32 atomics) ----
// wave = node. Loops over the node's edges in 16-edge MFMA tiles:
//   h = silu(A[n] + B[col] + d2*wl + b1)  (A[n] wave-uniform)
//   o = silu(h @ W2e + b2) per edge, row-masked, reduced over rows in-register.
__global__ __launch_bounds__(256, 4) void edgeagg_kernel(
        const unsigned short* __restrict__ Abf,
        const unsigned short* __restrict__ Bbf,
        const int* __restrict__ rowptr,
        const int* __restrict__ ecol,
        const float* __restrict__ ed2,
        const float* __restrict__ W1e,
        const float* __restrict__ b1e,
        const unsigned short* __restrict__ W2f,
        const float* __restrict__ b2e,
        float* __restrict__ agg) {
    const int t    = threadIdx.x;
    const int wv   = t >> 6;
    const int lane = t & 63;
    const int mrow = lane & 15;
    const int quad = lane >> 4;
    const int node = blockIdx.x * 4 + wv;        // 12500 * 4 = 50000 exact

    const int start = rowptr[node];
    const int d     = rowptr[node + 1] - start;

    // node accumulator: per-lane partials (sum over this lane's C rows) x 8 col-groups
    float nacc[8];
    #pragma unroll
    for (int k = 0; k < 8; ++k) nacc[k] = 0.f;

    // biases for C init
    float bias[8];
    #pragma unroll
    for (int k = 0; k < 8; ++k) bias[k] = b2e[k * 16 + mrow];

    // A chunks for this node (uniform across wave; per-lane offset by quad)
    const uint4* arow = (const uint4*)(Abf + ((size_t)node << 7));
    uint4 au[4];
    #pragma unroll
    for (int s = 0; s < 4; ++s) au[s] = arow[s * 4 + quad];

    const float4* wlp = (const float4*)(W1e + 256 * D);
    const float4* b1p = (const float4*)b1e;
    const uint4*  w2p = (const uint4*)W2f;

    for (int tb = 0; tb < d; tb += 16) {
        const int  ei16 = tb + mrow;
        const bool ve   = ei16 < d;
        const int  c    = ve ? ecol[start + ei16] : 0;
        const float d2  = ve ? ed2[start + ei16] : 0.f;
        const uint4* brow = (const uint4*)(Bbf + ((size_t)c << 7));

        floatx4 acc[8];
        #pragma unroll
        for (int k = 0; k < 8; ++k)
            acc[k] = (floatx4){bias[k], bias[k], bias[k], bias[k]};

        #pragma unroll
        for (int s = 0; s < 4; ++s) {
            uint4 bu = brow[s * 4 + quad];
            float4 wlA = wlp[s * 8 + quad * 2];
            float4 wlB = wlp[s * 8 + quad * 2 + 1];
            float4 bbA = b1p[s * 8 + quad * 2];
            float4 bbB = b1p[s * 8 + quad * 2 + 1];

            float a0, a1, a2, a3, a4, a5, a6, a7;
            float q0, q1, q2, q3, q4, q5, q6, q7;
            unpk(au[s].x, a0, a1); unpk(au[s].y, a2, a3);
            unpk(au[s].z, a4, a5); unpk(au[s].w, a6, a7);
            unpk(bu.x, q0, q1); unpk(bu.y, q2, q3);
            unpk(bu.z, q4, q5); unpk(bu.w, q6, q7);

            float h0 = ve ? silu_f(fmaf(d2, wlA.x, a0 + q0 + bbA.x)) : 0.f;
            float h1 = ve ? silu_f(fmaf(d2, wlA.y, a1 + q1 + bbA.y)) : 0.f;
            float h2 = ve ? silu_f(fmaf(d2, wlA.z, a2 + q2 + bbA.z)) : 0.f;
            float h3 = ve ? silu_f(fmaf(d2, wlA.w, a3 + q3 + bbA.w)) : 0.f;
            float h4 = ve ? silu_f(fmaf(d2, wlB.x, a4 + q4 + bbB.x)) : 0.f;
            float h5 = ve ? silu_f(fmaf(d2, wlB.y, a5 + q5 + bbB.y)) : 0.f;
            float h6 = ve ? silu_f(fmaf(d2, wlB.z, a6 + q6 + bbB.z)) : 0.f;
            float h7 = ve ? silu_f(fmaf(d2, wlB.w, a7 + q7 + bbB.w)) : 0.f;

            union { shortx8 v; __hip_bfloat162 p[4]; } af;
            af.p[0] = __float22bfloat162_rn(float2{h0, h1});
            af.p[1] = __float22bfloat162_rn(float2{h2, h3});
            af.p[2] = __float22bfloat162_rn(float2{h4, h5});
            af.p[3] = __float22bfloat162_rn(float2{h6, h7});

            const int base = (s * 4 + quad) * 128 + mrow;
            #pragma unroll
            for (int k = 0; k < 8; ++k) {
                union { uint4 u; shortx8 v; } bf;
                bf.u = w2p[base + k * 16];
                acc[k] = __builtin_amdgcn_mfma_f32_16x16x32_bf16(af.v, bf.v, acc[k], 0, 0, 0);
            }
        }

        // per-edge silu, mask pad rows, accumulate
        #pragma unroll
        for (int reg = 0; reg < 4; ++reg) {
            const bool vr = (tb + quad * 4 + reg) < d;
            #pragma unroll
            for (int k = 0; k < 8; ++k)
                nacc[k] += vr ? silu_f(acc[k][reg]) : 0.f;
        }
    }

    // cross-quad reduction: full column sums
    #pragma unroll
    for (int k = 0; k < 8; ++k) {
        float v = nacc[k];
        v += __shfl_xor(v, 16);
        v += __shfl_xor(v, 32);
        nacc[k] = v;
    }
    // each quad stores 2 of the 8 col-groups (cols n8*16+mrow)
    const int n8a = quad * 2, n8b = quad * 2 + 1;
    agg[(size_t)node * D + n8a * 16 + mrow] = nacc[n8a];
    agg[(size_t)node * D + n8b * 16 + mrow] = nacc[n8b];
}

// ---------------- node MLP + residual + LayerNorm ----------------
__global__ void node_kernel(const float* __restrict__ x,
                            const float* __restrict__ agg,
                            const float* __restrict__ W1n,
                            const float* __restrict__ b1n,
                            const float* __restrict__ W2n,
                            const float* __restrict__ b2n,
                            const float* __restrict__ gamma,
                            const float* __restrict__ beta,
                            float* __restrict__ out) {
    __shared__ float xs[TN][D];
    __shared__ float gs[TN][D];
    __shared__ float ts[TN][D];
    __shared__ float ys[TN][D];
    __shared__ float mus[TN], rsd[TN];

    const int j = threadIdx.x;            // 0..127
    const int n0 = blockIdx.x * TN;

    #pragma unroll
    for (int i = 0; i < TN; ++i) {
        int n = n0 + i;
        xs[i][j] = (n < NND) ? x[n * D + j] : 0.f;
        gs[i][j] = (n < NND) ? agg[n * D + j] : 0.f;
    }
    __syncthreads();

    float acc[TN];
    const float bb1 = b1n[j];
    #pragma unroll
    for (int i = 0; i < TN; ++i) acc[i] = bb1;

    for (int k4 = 0; k4 < D / 4; ++k4) {
        const int k = 4 * k4;
        float w0 = W1n[(k + 0) * D + j];
        float w1 = W1n[(k + 1) * D + j];
        float w2 = W1n[(k + 2) * D + j];
        float w3 = W1n[(k + 3) * D + j];
        #pragma unroll
        for (int i = 0; i < TN; ++i) {
            float4 v = ((const float4*)xs[i])[k4];
            acc[i] = fmaf(v.x, w0, acc[i]);
            acc[i] = fmaf(v.y, w1, acc[i]);
            acc[i] = fmaf(v.z, w2, acc[i]);
            acc[i] = fmaf(v.w, w3, acc[i]);
        }
    }
    for (int k4 = 0; k4 < D / 4; ++k4) {
        const int k = 4 * k4;
        float w0 = W1n[(D + k + 0) * D + j];
        float w1 = W1n[(D + k + 1) * D + j];
        float w2 = W1n[(D + k + 2) * D + j];
        float w3 = W1n[(D + k + 3) * D + j];
        #pragma unroll
        for (int i = 0; i < TN; ++i) {
            float4 v = ((const float4*)gs[i])[k4];
            acc[i] = fmaf(v.x, w0, acc[i]);
            acc[i] = fmaf(v.y, w1, acc[i]);
            acc[i] = fmaf(v.z, w2, acc[i]);
            acc[i] = fmaf(v.w, w3, acc[i]);
        }
    }
    #pragma unroll
    for (int i = 0; i < TN; ++i) ts[i][j] = silu_f(acc[i]);
    __syncthreads();

    float acc2[TN];
    const float bb2 = b2n[j];
    #pragma unroll
    for (int i = 0; i < TN; ++i) acc2[i] = bb2;

    for (int k4 = 0; k4 < D / 4; ++k4) {
        const int k = 4 * k4;
        float w0 = W2n[(k + 0) * D + j];
        float w1 = W2n[(k + 1) * D + j];
        float w2 = W2n[(k + 2) * D + j];
        float w3 = W2n[(k + 3) * D + j];
        #pragma unroll
        for (int i = 0; i < TN; ++i) {
            float4 t4 = ((const float4*)ts[i])[k4];
            acc2[i] = fmaf(t4.x, w0, acc2[i]);
            acc2[i] = fmaf(t4.y, w1, acc2[i]);
            acc2[i] = fmaf(t4.z, w2, acc2[i]);
            acc2[i] = fmaf(t4.w, w3, acc2[i]);
        }
    }
    #pragma unroll
    for (int i = 0; i < TN; ++i) ys[i][j] = xs[i][j] + acc2[i];
    __syncthreads();

    const int wave = j >> 6;
    const int lane = j & 63;
    for (int i = wave; i < TN; i += 2) {
        float a = ys[i][lane];
        float b = ys[i][lane + 64];
        float s  = a + b;
        float s2 = a * a + b * b;
        #pragma unroll
        for (int off = 32; off > 0; off >>= 1) {
            s  += __shfl_down(s, off);
            s2 += __shfl_down(s2, off);
        }
        if (lane == 0) {
            float mu  = s * (1.f / 128.f);
            float var = s2 * (1.f / 128.f) - mu * mu;
            mus[i] = mu;
            rsd[i] = rsqrtf(var + 1e-5f);
        }
    }
    __syncthreads();

    const float g  = gamma[j];
    const float bt = beta[j];
    #pragma unroll
    for (int i = 0; i < TN; ++i) {
        int n = n0 + i;
        if (n < NND) out[n * D + j] = (ys[i][j] - mus[i]) * rsd[i] * g + bt;
    }
}

extern "C" void kernel_launch(void* const* d_in, const int* in_sizes, int n_in,
                              void* d_out, int out_size, void* d_ws, size_t ws_size,
                              hipStream_t stream) {
    const float* x     = (const float*)d_in[0];
    const float* pos   = (const float*)d_in[1];
    const int*   ei    = (const int*)d_in[2];
    const float* W1e   = (const float*)d_in[3];
    const float* b1e   = (const float*)d_in[4];
    const float* W2e   = (const float*)d_in[5];
    const float* b2e   = (const float*)d_in[6];
    const float* W1n   = (const float*)d_in[7];
    const float* b1n   = (const float*)d_in[8];
    const float* W2n   = (const float*)d_in[9];
    const float* b2n   = (const float*)d_in[10];
    const float* gamma = (const float*)d_in[11];
    const float* beta  = (const float*)d_in[12];
    float* out = (float*)d_out;

    // ws layout (all 16B-aligned sizes)
    unsigned short* Abf    = (unsigned short*)d_ws;                  // 12.8 MB
    unsigned short* Bbf    = Abf + (size_t)NND * D;                  // 12.8 MB
    float*          agg    = (float*)(Bbf + (size_t)NND * D);        // 25.6 MB
    unsigned short* W2f    = (unsigned short*)(agg + (size_t)NND * D); // 32 KB
    int*            deg    = (int*)(W2f + D * D);                    // 50176 ints
    int*            part   = deg + 50176;                            // 50176 ints
    int*            bsum   = part + 50176;                           // 256
    int*            boff   = bsum + 256;                             // 256
    int*            rowptr = boff + 256;                             // 50004 (pad)
    int*            cursor = rowptr + 50004;                         // 50000
    int*            ecol   = cursor + 50000;                         // 800000
    float*          ed2    = (float*)(ecol + NE);                    // 800000

    // CSR build
    zero_kernel<<<128, 256, 0, stream>>>((float4*)deg, 50176 / 4);
    hist_kernel<<<NE / 256, 256, 0, stream>>>(ei, deg);
    scan1_kernel<<<NB1, 256, 0, stream>>>(deg, part, bsum);
    scan2_kernel<<<1, 256, 0, stream>>>(bsum, boff);
    scan3_kernel<<<197, 256, 0, stream>>>(part, boff, rowptr, cursor);
    scatter_kernel<<<NE / 256, 256, 0, stream>>>(ei, pos, cursor, ecol, ed2);

    // weights / features prep
    w2f_kernel<<<(D * D) / 256, 256, 0, stream>>>(W2e, W2f);
    precompute_kernel<<<(NND + TN - 1) / TN, D, 0, stream>>>(x, W1e, Abf, Bbf);

    // fused edge MLP + aggregation
    edgeagg_kernel<<<NND / 4, 256, 0, stream>>>(Abf, Bbf, rowptr, ecol, ed2,
                                                W1e, b1e, W2f, b2e, agg);

    // node MLP + residual + LN
    node_kernel<<<(NND + TN - 1) / TN, D, 0, stream>>>(x, agg, W1n, b1n, W2n, b2n,
                                                       gamma, beta, out);
}

// Round 5
// 726.356 us; speedup vs baseline: 2.4985x; 2.4985x over previous
//
#include <hip/hip_runtime.h>
#include <hip/hip_bf16.h>
#include <math.h>

#define D 128
#define NND 50000
#define NE 800000
#define TN 16          // nodes per block (precompute / node kernels)
#define NB1 196        // scan blocks: 196*256 = 50176 >= 50000

typedef __attribute__((ext_vector_type(8))) short shortx8;
typedef __attribute__((ext_vector_type(4))) float floatx4;

__device__ __forceinline__ float silu_f(float v) {
    return v / (1.0f + __expf(-v));
}
__device__ __forceinline__ unsigned short f2bf(float f) {
    union { float f; unsigned int u; } v; v.f = f;
    unsigned int u = v.u;
    u += 0x7fffu + ((u >> 16) & 1u);   // RNE
    return (unsigned short)(u >> 16);
}
__device__ __forceinline__ void unpk(unsigned int u, float& lo, float& hi) {
    union { unsigned int x; float f; } a, b;
    a.x = u << 16;
    b.x = u & 0xffff0000u;
    lo = a.f; hi = b.f;
}

// ---------------- zero (deg) ----------------
__global__ void zero_kernel(float4* __restrict__ p, int n4) {
    int i = blockIdx.x * blockDim.x + threadIdx.x;
    float4 z = make_float4(0.f, 0.f, 0.f, 0.f);
    for (; i < n4; i += gridDim.x * blockDim.x) p[i] = z;
}

// ---------------- CSR build ----------------
__global__ void hist_kernel(const int* __restrict__ ei, int* __restrict__ deg) {
    int e = blockIdx.x * 256 + threadIdx.x;     // NE = 3125*256 exactly
    atomicAdd(&deg[ei[e]], 1);
}

__global__ void scan1_kernel(const int* __restrict__ deg,
                             int* __restrict__ part, int* __restrict__ bsum) {
    __shared__ int s[256];
    const int tid = threadIdx.x;
    const int i = blockIdx.x * 256 + tid;
    int v = (i < NND) ? deg[i] : 0;
    s[tid] = v;
    __syncthreads();
    #pragma unroll
    for (int off = 1; off < 256; off <<= 1) {
        int t = (tid >= off) ? s[tid - off] : 0;
        __syncthreads();
        s[tid] += t;
        __syncthreads();
    }
    part[i] = s[tid] - v;                        // exclusive
    if (tid == 255) bsum[blockIdx.x] = s[255];
}

__global__ void scan2_kernel(const int* __restrict__ bsum, int* __restrict__ boff) {
    __shared__ int s[256];
    const int tid = threadIdx.x;
    int v = (tid < NB1) ? bsum[tid] : 0;
    s[tid] = v;
    __syncthreads();
    #pragma unroll
    for (int off = 1; off < 256; off <<= 1) {
        int t = (tid >= off) ? s[tid - off] : 0;
        __syncthreads();
        s[tid] += t;
        __syncthreads();
    }
    if (tid < NB1) boff[tid] = s[tid] - v;       // exclusive
}

__global__ void scan3_kernel(const int* __restrict__ part, const int* __restrict__ boff,
                             int* __restrict__ rowptr, int* __restrict__ cursor) {
    int i = blockIdx.x * 256 + threadIdx.x;
    if (i < NND) {
        int v = part[i] + boff[i >> 8];
        rowptr[i] = v;
        cursor[i] = v;
    } else if (i == NND) {
        rowptr[NND] = NE;
    }
}

// scatter col + dist2 into CSR order
__global__ void scatter_kernel(const int* __restrict__ ei, const float* __restrict__ pos,
                               int* __restrict__ cursor,
                               int* __restrict__ ecol, float* __restrict__ ed2) {
    int e = blockIdx.x * 256 + threadIdx.x;     // NE exact multiple of 256
    int r = ei[e], c = ei[NE + e];
    float dx = pos[r * 3 + 0] - pos[c * 3 + 0];
    float dy = pos[r * 3 + 1] - pos[c * 3 + 1];
    float dz = pos[r * 3 + 2] - pos[c * 3 + 2];
    int slot = atomicAdd(&cursor[r], 1);
    ecol[slot] = c;
    ed2[slot] = dx * dx + dy * dy + dz * dz;
}

// ---------------- weight prep: W2f (B-frag swizzle) + wlf (bf16 dist2 row) ---
__global__ void wprep_kernel(const float* __restrict__ W2e,
                             const float* __restrict__ W1e,
                             unsigned short* __restrict__ W2f,
                             unsigned short* __restrict__ wlf) {
    int f = blockIdx.x * 256 + threadIdx.x;   // 16384 total
    int j    = f & 7;
    int mrow = (f >> 3) & 15;
    int n    = (f >> 7) & 7;
    int quad = (f >> 10) & 3;
    int s    = f >> 12;
    int col = n * 16 + mrow;
    int k   = s * 32 + quad * 8 + j;
    W2f[f] = f2bf(W2e[k * D + col]);
    if (f < D) wlf[f] = f2bf(W1e[256 * D + f]);   // k-order == lane chunk order
}

// ---------------- A' = bf16(x @ W1e[0:128] + b1e), B = bf16(x @ W1e[128:256]) ----
__global__ void precompute_kernel(const float* __restrict__ x,
                                  const float* __restrict__ W1e,
                                  const float* __restrict__ b1e,
                                  unsigned short* __restrict__ A,
                                  unsigned short* __restrict__ Bm) {
    __shared__ float xs[TN][D];
    const int j = threadIdx.x;            // 0..127
    const int n0 = blockIdx.x * TN;

    #pragma unroll
    for (int i = 0; i < TN; ++i) {
        int n = n0 + i;
        xs[i][j] = (n < NND) ? x[n * D + j] : 0.f;
    }
    __syncthreads();

    float accA[TN], accB[TN];
    #pragma unroll
    for (int i = 0; i < TN; ++i) { accA[i] = 0.f; accB[i] = 0.f; }

    for (int k4 = 0; k4 < D / 4; ++k4) {
        const int k = 4 * k4;
        float wa0 = W1e[(k + 0) * D + j];
        float wa1 = W1e[(k + 1) * D + j];
        float wa2 = W1e[(k + 2) * D + j];
        float wa3 = W1e[(k + 3) * D + j];
        float wb0 = W1e[(D + k + 0) * D + j];
        float wb1 = W1e[(D + k + 1) * D + j];
        float wb2 = W1e[(D + k + 2) * D + j];
        float wb3 = W1e[(D + k + 3) * D + j];
        #pragma unroll
        for (int i = 0; i < TN; ++i) {
            float4 v = ((const float4*)xs[i])[k4];
            accA[i] = fmaf(v.x, wa0, accA[i]);
            accA[i] = fmaf(v.y, wa1, accA[i]);
            accA[i] = fmaf(v.z, wa2, accA[i]);
            accA[i] = fmaf(v.w, wa3, accA[i]);
            accB[i] = fmaf(v.x, wb0, accB[i]);
            accB[i] = fmaf(v.y, wb1, accB[i]);
            accB[i] = fmaf(v.z, wb2, accB[i]);
            accB[i] = fmaf(v.w, wb3, accB[i]);
        }
    }
    const float bb = b1e[j];
    #pragma unroll
    for (int i = 0; i < TN; ++i) {
        int n = n0 + i;
        if (n < NND) {
            A[n * D + j]  = f2bf(accA[i] + bb);   // b1 folded into A'
            Bm[n * D + j] = f2bf(accB[i]);
        }
    }
}

// ---------------- fused edge MLP + per-node aggregation ----------------
// wave = node. h = silu(A'[n] + B[col] + d2*wl); o = silu(h@W2e + b2) per edge,
// row-masked, reduced in-register. Register diet: invariants in packed bf16.
__global__ __launch_bounds__(256, 2) void edgeagg_kernel(
        const unsigned short* __restrict__ Abf,
        const unsigned short* __restrict__ Bbf,
        const int* __restrict__ rowptr,
        const int* __restrict__ ecol,
        const float* __restrict__ ed2,
        const unsigned short* __restrict__ wlf,
        const unsigned short* __restrict__ W2f,
        const float* __restrict__ b2e,
        float* __restrict__ agg) {
    const int t    = threadIdx.x;
    const int wv   = t >> 6;
    const int lane = t & 63;
    const int mrow = lane & 15;
    const int quad = lane >> 4;
    const int node = blockIdx.x * 4 + wv;        // 12500 * 4 = 50000 exact

    const int start = rowptr[node];
    const int d     = rowptr[node + 1] - start;

    // hoisted invariants (packed bf16: 16 + 16 VGPRs)
    const uint4* arow = (const uint4*)(Abf + ((size_t)node << 7));
    const uint4* wlq  = (const uint4*)wlf;
    uint4 au[4], wlu[4];
    #pragma unroll
    for (int s = 0; s < 4; ++s) {
        au[s]  = arow[s * 4 + quad];
        wlu[s] = wlq[s * 4 + quad];
    }
    float bias[8];
    #pragma unroll
    for (int k = 0; k < 8; ++k) bias[k] = b2e[k * 16 + mrow];

    float nacc[8];
    #pragma unroll
    for (int k = 0; k < 8; ++k) nacc[k] = 0.f;

    const uint4* w2p = (const uint4*)W2f;

    for (int tb = 0; tb < d; tb += 16) {
        const int  ei16 = tb + mrow;
        const bool ve   = ei16 < d;
        const int  idx  = start + (ve ? ei16 : 0);
        const int  c    = ecol[idx];
        float d2        = ed2[idx];
        d2 = ve ? d2 : 0.f;
        const uint4* brow = (const uint4*)(Bbf + ((size_t)c << 7));

        floatx4 acc[8];
        #pragma unroll
        for (int k = 0; k < 8; ++k) acc[k] = (floatx4){0.f, 0.f, 0.f, 0.f};

        #pragma unroll
        for (int s = 0; s < 4; ++s) {
            uint4 bu = brow[s * 4 + quad];

            float a0, a1, a2, a3, a4, a5, a6, a7;
            float q0, q1, q2, q3, q4, q5, q6, q7;
            float w0, w1, w2, w3, w4, w5, w6, w7;
            unpk(au[s].x, a0, a1); unpk(au[s].y, a2, a3);
            unpk(au[s].z, a4, a5); unpk(au[s].w, a6, a7);
            unpk(bu.x, q0, q1); unpk(bu.y, q2, q3);
            unpk(bu.z, q4, q5); unpk(bu.w, q6, q7);
            unpk(wlu[s].x, w0, w1); unpk(wlu[s].y, w2, w3);
            unpk(wlu[s].z, w4, w5); unpk(wlu[s].w, w6, w7);

            float h0 = silu_f(fmaf(d2, w0, a0 + q0));
            float h1 = silu_f(fmaf(d2, w1, a1 + q1));
            float h2 = silu_f(fmaf(d2, w2, a2 + q2));
            float h3 = silu_f(fmaf(d2, w3, a3 + q3));
            float h4 = silu_f(fmaf(d2, w4, a4 + q4));
            float h5 = silu_f(fmaf(d2, w5, a5 + q5));
            float h6 = silu_f(fmaf(d2, w6, a6 + q6));
            float h7 = silu_f(fmaf(d2, w7, a7 + q7));

            union { shortx8 v; __hip_bfloat162 p[4]; } af;
            af.p[0] = __float22bfloat162_rn(float2{h0, h1});
            af.p[1] = __float22bfloat162_rn(float2{h2, h3});
            af.p[2] = __float22bfloat162_rn(float2{h4, h5});
            af.p[3] = __float22bfloat162_rn(float2{h6, h7});

            const int base = (s * 4 + quad) * 128 + mrow;
            #pragma unroll
            for (int k = 0; k < 8; ++k) {
                union { uint4 u; shortx8 v; } bf;
                bf.u = w2p[base + k * 16];
                acc[k] = __builtin_amdgcn_mfma_f32_16x16x32_bf16(af.v, bf.v, acc[k], 0, 0, 0);
            }
        }

        // per-edge: add bias, silu, mask pad rows, accumulate
        #pragma unroll
        for (int reg = 0; reg < 4; ++reg) {
            const bool vr = (tb + quad * 4 + reg) < d;
            #pragma unroll
            for (int k = 0; k < 8; ++k)
                nacc[k] += vr ? silu_f(acc[k][reg] + bias[k]) : 0.f;
        }
    }

    // cross-quad reduction: full column sums
    #pragma unroll
    for (int k = 0; k < 8; ++k) {
        float v = nacc[k];
        v += __shfl_xor(v, 16);
        v += __shfl_xor(v, 32);
        nacc[k] = v;
    }
    const int n8a = quad * 2, n8b = quad * 2 + 1;
    agg[(size_t)node * D + n8a * 16 + mrow] = nacc[n8a];
    agg[(size_t)node * D + n8b * 16 + mrow] = nacc[n8b];
}

// ---------------- node MLP + residual + LayerNorm ----------------
__global__ void node_kernel(const float* __restrict__ x,
                            const float* __restrict__ agg,
                            const float* __restrict__ W1n,
                            const float* __restrict__ b1n,
                            const float* __restrict__ W2n,
                            const float* __restrict__ b2n,
                            const float* __restrict__ gamma,
                            const float* __restrict__ beta,
                            float* __restrict__ out) {
    __shared__ float xs[TN][D];
    __shared__ float gs[TN][D];
    __shared__ float ts[TN][D];
    __shared__ float ys[TN][D];
    __shared__ float mus[TN], rsd[TN];

    const int j = threadIdx.x;            // 0..127
    const int n0 = blockIdx.x * TN;

    #pragma unroll
    for (int i = 0; i < TN; ++i) {
        int n = n0 + i;
        xs[i][j] = (n < NND) ? x[n * D + j] : 0.f;
        gs[i][j] = (n < NND) ? agg[n * D + j] : 0.f;
    }
    __syncthreads();

    float acc[TN];
    const float bb1 = b1n[j];
    #pragma unroll
    for (int i = 0; i < TN; ++i) acc[i] = bb1;

    for (int k4 = 0; k4 < D / 4; ++k4) {
        const int k = 4 * k4;
        float w0 = W1n[(k + 0) * D + j];
        float w1 = W1n[(k + 1) * D + j];
        float w2 = W1n[(k + 2) * D + j];
        float w3 = W1n[(k + 3) * D + j];
        #pragma unroll
        for (int i = 0; i < TN; ++i) {
            float4 v = ((const float4*)xs[i])[k4];
            acc[i] = fmaf(v.x, w0, acc[i]);
            acc[i] = fmaf(v.y, w1, acc[i]);
            acc[i] = fmaf(v.z, w2, acc[i]);
            acc[i] = fmaf(v.w, w3, acc[i]);
        }
    }
    for (int k4 = 0; k4 < D / 4; ++k4) {
        const int k = 4 * k4;
        float w0 = W1n[(D + k + 0) * D + j];
        float w1 = W1n[(D + k + 1) * D + j];
        float w2 = W1n[(D + k + 2) * D + j];
        float w3 = W1n[(D + k + 3) * D + j];
        #pragma unroll
        for (int i = 0; i < TN; ++i) {
            float4 v = ((const float4*)gs[i])[k4];
            acc[i] = fmaf(v.x, w0, acc[i]);
            acc[i] = fmaf(v.y, w1, acc[i]);
            acc[i] = fmaf(v.z, w2, acc[i]);
            acc[i] = fmaf(v.w, w3, acc[i]);
        }
    }
    #pragma unroll
    for (int i = 0; i < TN; ++i) ts[i][j] = silu_f(acc[i]);
    __syncthreads();

    float acc2[TN];
    const float bb2 = b2n[j];
    #pragma unroll
    for (int i = 0; i < TN; ++i) acc2[i] = bb2;

    for (int k4 = 0; k4 < D / 4; ++k4) {
        const int k = 4 * k4;
        float w0 = W2n[(k + 0) * D + j];
        float w1 = W2n[(k + 1) * D + j];
        float w2 = W2n[(k + 2) * D + j];
        float w3 = W2n[(k + 3) * D + j];
        #pragma unroll
        for (int i = 0; i < TN; ++i) {
            float4 t4 = ((const float4*)ts[i])[k4];
            acc2[i] = fmaf(t4.x, w0, acc2[i]);
            acc2[i] = fmaf(t4.y, w1, acc2[i]);
            acc2[i] = fmaf(t4.z, w2, acc2[i]);
            acc2[i] = fmaf(t4.w, w3, acc2[i]);
        }
    }
    #pragma unroll
    for (int i = 0; i < TN; ++i) ys[i][j] = xs[i][j] + acc2[i];
    __syncthreads();

    const int wave = j >> 6;
    const int lane = j & 63;
    for (int i = wave; i < TN; i += 2) {
        float a = ys[i][lane];
        float b = ys[i][lane + 64];
        float s  = a + b;
        float s2 = a * a + b * b;
        #pragma unroll
        for (int off = 32; off > 0; off >>= 1) {
            s  += __shfl_down(s, off);
            s2 += __shfl_down(s2, off);
        }
        if (lane == 0) {
            float mu  = s * (1.f / 128.f);
            float var = s2 * (1.f / 128.f) - mu * mu;
            mus[i] = mu;
            rsd[i] = rsqrtf(var + 1e-5f);
        }
    }
    __syncthreads();

    const float g  = gamma[j];
    const float bt = beta[j];
    #pragma unroll
    for (int i = 0; i < TN; ++i) {
        int n = n0 + i;
        if (n < NND) out[n * D + j] = (ys[i][j] - mus[i]) * rsd[i] * g + bt;
    }
}

extern "C" void kernel_launch(void* const* d_in, const int* in_sizes, int n_in,
                              void* d_out, int out_size, void* d_ws, size_t ws_size,
                              hipStream_t stream) {
    const float* x     = (const float*)d_in[0];
    const float* pos   = (const float*)d_in[1];
    const int*   ei    = (const int*)d_in[2];
    const float* W1e   = (const float*)d_in[3];
    const float* b1e   = (const float*)d_in[4];
    const float* W2e   = (const float*)d_in[5];
    const float* b2e   = (const float*)d_in[6];
    const float* W1n   = (const float*)d_in[7];
    const float* b1n   = (const float*)d_in[8];
    const float* W2n   = (const float*)d_in[9];
    const float* b2n   = (const float*)d_in[10];
    const float* gamma = (const float*)d_in[11];
    const float* beta  = (const float*)d_in[12];
    float* out = (float*)d_out;

    // ws layout (all 16B-aligned sizes)
    unsigned short* Abf    = (unsigned short*)d_ws;                  // 12.8 MB
    unsigned short* Bbf    = Abf + (size_t)NND * D;                  // 12.8 MB
    float*          agg    = (float*)(Bbf + (size_t)NND * D);        // 25.6 MB
    unsigned short* W2f    = (unsigned short*)(agg + (size_t)NND * D); // 32 KB
    unsigned short* wlf    = W2f + D * D;                            // 128 bf16
    int*            deg    = (int*)(wlf + 128);                      // 50176 ints
    int*            part   = deg + 50176;                            // 50176 ints
    int*            bsum   = part + 50176;                           // 256
    int*            boff   = bsum + 256;                             // 256
    int*            rowptr = boff + 256;                             // 50004 (pad)
    int*            cursor = rowptr + 50004;                         // 50000
    int*            ecol   = cursor + 50000;                         // 800000
    float*          ed2    = (float*)(ecol + NE);                    // 800000

    // CSR build
    zero_kernel<<<128, 256, 0, stream>>>((float4*)deg, 50176 / 4);
    hist_kernel<<<NE / 256, 256, 0, stream>>>(ei, deg);
    scan1_kernel<<<NB1, 256, 0, stream>>>(deg, part, bsum);
    scan2_kernel<<<1, 256, 0, stream>>>(bsum, boff);
    scan3_kernel<<<197, 256, 0, stream>>>(part, boff, rowptr, cursor);
    scatter_kernel<<<NE / 256, 256, 0, stream>>>(ei, pos, cursor, ecol, ed2);

    // weights / features prep
    wprep_kernel<<<(D * D) / 256, 256, 0, stream>>>(W2e, W1e, W2f, wlf);
    precompute_kernel<<<(NND + TN - 1) / TN, D, 0, stream>>>(x, W1e, b1e, Abf, Bbf);

    // fused edge MLP + aggregation
    edgeagg_kernel<<<NND / 4, 256, 0, stream>>>(Abf, Bbf, rowptr, ecol, ed2,
                                                wlf, W2f, b2e, agg);

    // node MLP + residual + LN
    node_kernel<<<(NND + TN - 1) / TN, D, 0, stream>>>(x, agg, W1n, b1n, W2n, b2n,
                                                       gamma, beta, out);
}

// Round 7
// 528.297 us; speedup vs baseline: 3.4352x; 1.3749x over previous
//
#include <hip/hip_runtime.h>
#include <hip/hip_bf16.h>
#include <math.h>

#define D 128
#define NND 50000
#define NE 800000
#define NB1 196        // scan blocks: 196*256 = 50176 >= 50000
#define TPITCH 152     // ushort pitch for node transpose tile (304 B = 19*16)

typedef __attribute__((ext_vector_type(8))) short shortx8;
typedef __attribute__((ext_vector_type(4))) float floatx4;

__device__ __forceinline__ float silu_f(float v) {
    return v / (1.0f + __expf(-v));
}
__device__ __forceinline__ unsigned short f2bf(float f) {
    union { float f; unsigned int u; } v; v.f = f;
    unsigned int u = v.u;
    u += 0x7fffu + ((u >> 16) & 1u);   // RNE
    return (unsigned short)(u >> 16);
}
__device__ __forceinline__ void unpk(unsigned int u, float& lo, float& hi) {
    union { unsigned int x; float f; } a, b;
    a.x = u << 16;
    b.x = u & 0xffff0000u;
    lo = a.f; hi = b.f;
}

// ---------------- zero (deg) ----------------
__global__ void zero_kernel(float4* __restrict__ p, int n4) {
    int i = blockIdx.x * blockDim.x + threadIdx.x;
    float4 z = make_float4(0.f, 0.f, 0.f, 0.f);
    for (; i < n4; i += gridDim.x * blockDim.x) p[i] = z;
}

// ---------------- CSR build ----------------
__global__ void hist_kernel(const int* __restrict__ ei, int* __restrict__ deg) {
    int e = blockIdx.x * 256 + threadIdx.x;     // NE = 3125*256 exactly
    atomicAdd(&deg[ei[e]], 1);
}

__global__ void scan1_kernel(const int* __restrict__ deg,
                             int* __restrict__ part, int* __restrict__ bsum) {
    __shared__ int s[256];
    const int tid = threadIdx.x;
    const int i = blockIdx.x * 256 + tid;
    int v = (i < NND) ? deg[i] : 0;
    s[tid] = v;
    __syncthreads();
    #pragma unroll
    for (int off = 1; off < 256; off <<= 1) {
        int t = (tid >= off) ? s[tid - off] : 0;
        __syncthreads();
        s[tid] += t;
        __syncthreads();
    }
    part[i] = s[tid] - v;                        // exclusive
    if (tid == 255) bsum[blockIdx.x] = s[255];
}

__global__ void scan2_kernel(const int* __restrict__ bsum, int* __restrict__ boff) {
    __shared__ int s[256];
    const int tid = threadIdx.x;
    int v = (tid < NB1) ? bsum[tid] : 0;
    s[tid] = v;
    __syncthreads();
    #pragma unroll
    for (int off = 1; off < 256; off <<= 1) {
        int t = (tid >= off) ? s[tid - off] : 0;
        __syncthreads();
        s[tid] += t;
        __syncthreads();
    }
    if (tid < NB1) boff[tid] = s[tid] - v;       // exclusive
}

__global__ void scan3_kernel(const int* __restrict__ part, const int* __restrict__ boff,
                             int* __restrict__ rowptr, int* __restrict__ cursor) {
    int i = blockIdx.x * 256 + threadIdx.x;
    if (i < NND) {
        int v = part[i] + boff[i >> 8];
        rowptr[i] = v;
        cursor[i] = v;
    } else if (i == NND) {
        rowptr[NND] = NE;
    }
}

// scatter col + dist2 into CSR order
__global__ void scatter_kernel(const int* __restrict__ ei, const float* __restrict__ pos,
                               int* __restrict__ cursor,
                               int* __restrict__ ecol, float* __restrict__ ed2) {
    int e = blockIdx.x * 256 + threadIdx.x;     // NE exact multiple of 256
    int r = ei[e], c = ei[NE + e];
    float dx = pos[r * 3 + 0] - pos[c * 3 + 0];
    float dy = pos[r * 3 + 1] - pos[c * 3 + 1];
    float dz = pos[r * 3 + 2] - pos[c * 3 + 2];
    int slot = atomicAdd(&cursor[r], 1);
    ecol[slot] = c;
    ed2[slot] = dx * dx + dy * dy + dz * dz;
}

// ---------------- generic B-fragment weight swizzle ----------------
// Wf flat f = (((ks*4+quad)*128)+n*16+mrow)*8+j  <->  W[k=ks*32+quad*8+j][col=n*16+mrow]
// W is [K][128] row-major fp32; grid must cover K*128 exactly.
__global__ void wswz_kernel(const float* __restrict__ W,
                            unsigned short* __restrict__ Wf) {
    int f = blockIdx.x * 256 + threadIdx.x;
    int j    = f & 7;
    int mrow = (f >> 3) & 15;
    int n    = (f >> 7) & 7;
    int rest = f >> 10;
    int quad = rest & 3;
    int ks   = rest >> 2;
    int col = n * 16 + mrow;
    int k   = ks * 32 + quad * 8 + j;
    Wf[f] = f2bf(W[k * D + col]);
}

// wlf: bf16 copy of W1e row 256 (dist2 weights), k-order = lane chunk order
__global__ void wlf_kernel(const float* __restrict__ W1e,
                           unsigned short* __restrict__ wlf) {
    int t = threadIdx.x;   // 128 threads
    wlf[t] = f2bf(W1e[256 * D + t]);
}

// ---------------- x -> bf16 ----------------
__global__ void x2bf_kernel(const float4* __restrict__ x4, uint2* __restrict__ xbf) {
    int i = blockIdx.x * 256 + threadIdx.x;   // NND*D/4 = 1.6M exact
    float4 v = x4[i];
    uint2 o;
    o.x = (unsigned int)f2bf(v.x) | ((unsigned int)f2bf(v.y) << 16);
    o.y = (unsigned int)f2bf(v.z) | ((unsigned int)f2bf(v.w) << 16);
    xbf[i] = o;
}

// ---------------- A' = bf16(x@W1e_top + b1e), B = bf16(x@W1e_bot)  [MFMA] ----
// wave = 16-node tile; 3125 tiles total (50000/16 exact).
__global__ __launch_bounds__(256) void precompute_kernel(
        const unsigned short* __restrict__ xbf,
        const unsigned short* __restrict__ w1f,   // 256x128 swizzled
        const float* __restrict__ b1e,
        unsigned short* __restrict__ A,
        unsigned short* __restrict__ Bm) {
    const int t    = threadIdx.x;
    const int wv   = t >> 6;
    const int lane = t & 63;
    const int mrow = lane & 15;
    const int quad = lane >> 4;
    const int tile = blockIdx.x * 4 + wv;
    if (tile >= 3125) return;
    const int n0 = tile * 16;

    const uint4* xrow = (const uint4*)(xbf + ((size_t)(n0 + mrow) << 7));
    const uint4* wp   = (const uint4*)w1f;

    floatx4 accA[8], accB[8];
    #pragma unroll
    for (int n = 0; n < 8; ++n) {
        accA[n] = (floatx4){0.f, 0.f, 0.f, 0.f};
        accB[n] = (floatx4){0.f, 0.f, 0.f, 0.f};
    }

    #pragma unroll
    for (int s = 0; s < 4; ++s) {
        union { uint4 u; shortx8 v; } af;
        af.u = xrow[s * 4 + quad];
        const int baseA = (s * 4 + quad) * 128 + mrow;
        const int baseB = ((s + 4) * 4 + quad) * 128 + mrow;
        #pragma unroll
        for (int n = 0; n < 8; ++n) {
            union { uint4 u; shortx8 v; } bfA, bfB;
            bfA.u = wp[baseA + n * 16];
            bfB.u = wp[baseB + n * 16];
            accA[n] = __builtin_amdgcn_mfma_f32_16x16x32_bf16(af.v, bfA.v, accA[n], 0, 0, 0);
            accB[n] = __builtin_amdgcn_mfma_f32_16x16x32_bf16(af.v, bfB.v, accB[n], 0, 0, 0);
        }
    }

    float bb[8];
    #pragma unroll
    for (int n = 0; n < 8; ++n) bb[n] = b1e[n * 16 + mrow];

    #pragma unroll
    for (int reg = 0; reg < 4; ++reg) {
        const int node = n0 + quad * 4 + reg;
        #pragma unroll
        for (int n = 0; n < 8; ++n) {
            const int col = n * 16 + mrow;
            A[(size_t)node * D + col]  = f2bf(accA[n][reg] + bb[n]);
            Bm[(size_t)node * D + col] = f2bf(accB[n][reg]);
        }
    }
}

// ---------------- fused edge MLP + per-node aggregation ----------------
// wave = node; writes agg in bf16 (feeds node-kernel A-frags directly).
__global__ __launch_bounds__(256, 2) void edgeagg_kernel(
        const unsigned short* __restrict__ Abf,
        const unsigned short* __restrict__ Bbf,
        const int* __restrict__ rowptr,
        const int* __restrict__ ecol,
        const float* __restrict__ ed2,
        const unsigned short* __restrict__ wlf,
        const unsigned short* __restrict__ W2f,
        const float* __restrict__ b2e,
        unsigned short* __restrict__ aggbf) {
    const int t    = threadIdx.x;
    const int wv   = t >> 6;
    const int lane = t & 63;
    const int mrow = lane & 15;
    const int quad = lane >> 4;
    const int node = blockIdx.x * 4 + wv;        // 12500 * 4 = 50000 exact

    const int start = rowptr[node];
    const int d     = rowptr[node + 1] - start;

    const uint4* arow = (const uint4*)(Abf + ((size_t)node << 7));
    const uint4* wlq  = (const uint4*)wlf;
    uint4 au[4], wlu[4];
    #pragma unroll
    for (int s = 0; s < 4; ++s) {
        au[s]  = arow[s * 4 + quad];
        wlu[s] = wlq[s * 4 + quad];
    }
    float bias[8];
    #pragma unroll
    for (int k = 0; k < 8; ++k) bias[k] = b2e[k * 16 + mrow];

    float nacc[8];
    #pragma unroll
    for (int k = 0; k < 8; ++k) nacc[k] = 0.f;

    const uint4* w2p = (const uint4*)W2f;

    for (int tb = 0; tb < d; tb += 16) {
        const int  ei16 = tb + mrow;
        const bool ve   = ei16 < d;
        const int  idx  = start + (ve ? ei16 : 0);
        const int  c    = ecol[idx];
        float d2        = ed2[idx];
        d2 = ve ? d2 : 0.f;
        const uint4* brow = (const uint4*)(Bbf + ((size_t)c << 7));

        floatx4 acc[8];
        #pragma unroll
        for (int k = 0; k < 8; ++k) acc[k] = (floatx4){0.f, 0.f, 0.f, 0.f};

        #pragma unroll
        for (int s = 0; s < 4; ++s) {
            uint4 bu = brow[s * 4 + quad];

            float a0, a1, a2, a3, a4, a5, a6, a7;
            float q0, q1, q2, q3, q4, q5, q6, q7;
            float w0, w1, w2, w3, w4, w5, w6, w7;
            unpk(au[s].x, a0, a1); unpk(au[s].y, a2, a3);
            unpk(au[s].z, a4, a5); unpk(au[s].w, a6, a7);
            unpk(bu.x, q0, q1); unpk(bu.y, q2, q3);
            unpk(bu.z, q4, q5); unpk(bu.w, q6, q7);
            unpk(wlu[s].x, w0, w1); unpk(wlu[s].y, w2, w3);
            unpk(wlu[s].z, w4, w5); unpk(wlu[s].w, w6, w7);

            float h0 = silu_f(fmaf(d2, w0, a0 + q0));
            float h1 = silu_f(fmaf(d2, w1, a1 + q1));
            float h2 = silu_f(fmaf(d2, w2, a2 + q2));
            float h3 = silu_f(fmaf(d2, w3, a3 + q3));
            float h4 = silu_f(fmaf(d2, w4, a4 + q4));
            float h5 = silu_f(fmaf(d2, w5, a5 + q5));
            float h6 = silu_f(fmaf(d2, w6, a6 + q6));
            float h7 = silu_f(fmaf(d2, w7, a7 + q7));

            union { shortx8 v; __hip_bfloat162 p[4]; } af;
            af.p[0] = __float22bfloat162_rn(float2{h0, h1});
            af.p[1] = __float22bfloat162_rn(float2{h2, h3});
            af.p[2] = __float22bfloat162_rn(float2{h4, h5});
            af.p[3] = __float22bfloat162_rn(float2{h6, h7});

            const int base = (s * 4 + quad) * 128 + mrow;
            #pragma unroll
            for (int k = 0; k < 8; ++k) {
                union { uint4 u; shortx8 v; } bf;
                bf.u = w2p[base + k * 16];
                acc[k] = __builtin_amdgcn_mfma_f32_16x16x32_bf16(af.v, bf.v, acc[k], 0, 0, 0);
            }
        }

        #pragma unroll
        for (int reg = 0; reg < 4; ++reg) {
            const bool vr = (tb + quad * 4 + reg) < d;
            #pragma unroll
            for (int k = 0; k < 8; ++k)
                nacc[k] += vr ? silu_f(acc[k][reg] + bias[k]) : 0.f;
        }
    }

    #pragma unroll
    for (int k = 0; k < 8; ++k) {
        float v = nacc[k];
        v += __shfl_xor(v, 16);
        v += __shfl_xor(v, 32);
        nacc[k] = v;
    }
    const int n8a = quad * 2, n8b = quad * 2 + 1;
    aggbf[(size_t)node * D + n8a * 16 + mrow] = f2bf(nacc[n8a]);
    aggbf[(size_t)node * D + n8b * 16 + mrow] = f2bf(nacc[n8b]);
}

// ---------------- node MLP + residual + LayerNorm  [MFMA] ----------------
// 1 wave per block, block = 16 nodes. Stage1 K=256 ([x|agg] bf16), transpose
// via LDS (304 B pitch), stage2 K=128, epilogue residual + LN via quad shfl.
__global__ __launch_bounds__(64) void node_kernel(
        const unsigned short* __restrict__ xbf,
        const unsigned short* __restrict__ aggbf,
        const unsigned short* __restrict__ w1nf,  // 256x128 swizzled
        const float* __restrict__ b1n,
        const unsigned short* __restrict__ w2nf,  // 128x128 swizzled
        const float* __restrict__ b2n,
        const float* __restrict__ x,
        const float* __restrict__ gamma,
        const float* __restrict__ beta,
        float* __restrict__ out) {
    __shared__ __align__(16) unsigned short ts[16 * TPITCH];
    const int lane = threadIdx.x;
    const int mrow = lane & 15;
    const int quad = lane >> 4;
    const int n0 = blockIdx.x * 16;      // 3125 blocks exact

    const uint4* xrow = (const uint4*)(xbf + ((size_t)(n0 + mrow) << 7));
    const uint4* grow = (const uint4*)(aggbf + ((size_t)(n0 + mrow) << 7));
    const uint4* w1p  = (const uint4*)w1nf;
    const uint4* w2p  = (const uint4*)w2nf;

    floatx4 acc[8];
    #pragma unroll
    for (int n = 0; n < 8; ++n) {
        float b = b1n[n * 16 + mrow];
        acc[n] = (floatx4){b, b, b, b};
    }

    #pragma unroll
    for (int s = 0; s < 4; ++s) {
        union { uint4 u; shortx8 v; } af;
        af.u = xrow[s * 4 + quad];
        const int base = (s * 4 + quad) * 128 + mrow;
        #pragma unroll
        for (int n = 0; n < 8; ++n) {
            union { uint4 u; shortx8 v; } bf;
            bf.u = w1p[base + n * 16];
            acc[n] = __builtin_amdgcn_mfma_f32_16x16x32_bf16(af.v, bf.v, acc[n], 0, 0, 0);
        }
    }
    #pragma unroll
    for (int s = 0; s < 4; ++s) {
        union { uint4 u; shortx8 v; } af;
        af.u = grow[s * 4 + quad];
        const int base = ((s + 4) * 4 + quad) * 128 + mrow;
        #pragma unroll
        for (int n = 0; n < 8; ++n) {
            union { uint4 u; shortx8 v; } bf;
            bf.u = w1p[base + n * 16];
            acc[n] = __builtin_amdgcn_mfma_f32_16x16x32_bf16(af.v, bf.v, acc[n], 0, 0, 0);
        }
    }

    // silu -> LDS (row-major [m][col], transpose for stage-2 A-frags)
    #pragma unroll
    for (int reg = 0; reg < 4; ++reg) {
        const int m = quad * 4 + reg;
        #pragma unroll
        for (int n = 0; n < 8; ++n)
            ts[m * TPITCH + n * 16 + mrow] = f2bf(silu_f(acc[n][reg]));
    }
    __syncthreads();   // single wave: cheap; guarantees LDS RAW ordering

    floatx4 acc2[8];
    #pragma unroll
    for (int n = 0; n < 8; ++n) {
        float b = b2n[n * 16 + mrow];
        acc2[n] = (floatx4){b, b, b, b};
    }
    #pragma unroll
    for (int s = 0; s < 4; ++s) {
        shortx8 af2 = *(const shortx8*)((const char*)ts +
                        mrow * (TPITCH * 2) + (s * 4 + quad) * 16);
        const int base = (s * 4 + quad) * 128 + mrow;
        #pragma unroll
        for (int n = 0; n < 8; ++n) {
            union { uint4 u; shortx8 v; } bf;
            bf.u = w2p[base + n * 16];
            acc2[n] = __builtin_amdgcn_mfma_f32_16x16x32_bf16(af2, bf.v, acc2[n], 0, 0, 0);
        }
    }

    // epilogue: residual + LayerNorm (reduce over the 16 lanes of each quad)
    float g[8], bt[8];
    #pragma unroll
    for (int n = 0; n < 8; ++n) {
        g[n]  = gamma[n * 16 + mrow];
        bt[n] = beta[n * 16 + mrow];
    }
    #pragma unroll
    for (int reg = 0; reg < 4; ++reg) {
        const int node = n0 + quad * 4 + reg;
        float u[8];
        float s1 = 0.f, s2 = 0.f;
        #pragma unroll
        for (int n = 0; n < 8; ++n) {
            u[n] = acc2[n][reg] + x[(size_t)node * D + n * 16 + mrow];
            s1 += u[n];
            s2 += u[n] * u[n];
        }
        #pragma unroll
        for (int off = 1; off < 16; off <<= 1) {
            s1 += __shfl_xor(s1, off);
            s2 += __shfl_xor(s2, off);
        }
        const float mu  = s1 * (1.f / 128.f);
        const float var = s2 * (1.f / 128.f) - mu * mu;
        const float rs  = rsqrtf(var + 1e-5f);
        #pragma unroll
        for (int n = 0; n < 8; ++n)
            out[(size_t)node * D + n * 16 + mrow] = (u[n] - mu) * rs * g[n] + bt[n];
    }
}

extern "C" void kernel_launch(void* const* d_in, const int* in_sizes, int n_in,
                              void* d_out, int out_size, void* d_ws, size_t ws_size,
                              hipStream_t stream) {
    const float* x     = (const float*)d_in[0];
    const float* pos   = (const float*)d_in[1];
    const int*   ei    = (const int*)d_in[2];
    const float* W1e   = (const float*)d_in[3];
    const float* b1e   = (const float*)d_in[4];
    const float* W2e   = (const float*)d_in[5];
    const float* b2e   = (const float*)d_in[6];
    const float* W1n   = (const float*)d_in[7];
    const float* b1n   = (const float*)d_in[8];
    const float* W2n   = (const float*)d_in[9];
    const float* b2n   = (const float*)d_in[10];
    const float* gamma = (const float*)d_in[11];
    const float* beta  = (const float*)d_in[12];
    float* out = (float*)d_out;

    // ws layout (all offsets 16B-aligned)
    unsigned short* Abf    = (unsigned short*)d_ws;                   // 12.8 MB
    unsigned short* Bbf    = Abf + (size_t)NND * D;                   // 12.8 MB
    unsigned short* aggbf  = Bbf + (size_t)NND * D;                   // 12.8 MB
    unsigned short* xbf    = aggbf + (size_t)NND * D;                 // 12.8 MB
    unsigned short* w1f    = xbf + (size_t)NND * D;                   // 64 KB (256x128)
    unsigned short* w1nf   = w1f + 256 * D;                           // 64 KB (256x128)
    unsigned short* w2f    = w1nf + 256 * D;                          // 32 KB (128x128)
    unsigned short* w2nf   = w2f + D * D;                             // 32 KB (128x128)
    unsigned short* wlf    = w2nf + D * D;                            // 256 B
    int*            deg    = (int*)(wlf + 128);
    int*            part   = deg + 50176;
    int*            bsum   = part + 50176;
    int*            boff   = bsum + 256;
    int*            rowptr = boff + 256;                              // 50004
    int*            cursor = rowptr + 50004;
    int*            ecol   = cursor + 50000;                          // 800000
    float*          ed2    = (float*)(ecol + NE);                     // 800000

    // CSR build
    zero_kernel<<<64, 256, 0, stream>>>((float4*)deg, 50176 / 4);
    hist_kernel<<<NE / 256, 256, 0, stream>>>(ei, deg);
    scan1_kernel<<<NB1, 256, 0, stream>>>(deg, part, bsum);
    scan2_kernel<<<1, 256, 0, stream>>>(bsum, boff);
    scan3_kernel<<<197, 256, 0, stream>>>(part, boff, rowptr, cursor);
    scatter_kernel<<<NE / 256, 256, 0, stream>>>(ei, pos, cursor, ecol, ed2);

    // weight swizzles + x conversion
    wswz_kernel<<<(256 * D) / 256, 256, 0, stream>>>(W1e, w1f);   // K=256 (rows 0..255)
    wswz_kernel<<<(256 * D) / 256, 256, 0, stream>>>(W1n, w1nf);  // K=256
    wswz_kernel<<<(D * D) / 256, 256, 0, stream>>>(W2e, w2f);     // K=128
    wswz_kernel<<<(D * D) / 256, 256, 0, stream>>>(W2n, w2nf);    // K=128
    wlf_kernel<<<1, 128, 0, stream>>>(W1e, wlf);
    x2bf_kernel<<<(NND * D / 4) / 256, 256, 0, stream>>>((const float4*)x, (uint2*)xbf);

    // A'/B precompute (MFMA)
    precompute_kernel<<<782, 256, 0, stream>>>(xbf, w1f, b1e, Abf, Bbf);

    // fused edge MLP + aggregation (bf16 agg out)
    edgeagg_kernel<<<NND / 4, 256, 0, stream>>>(Abf, Bbf, rowptr, ecol, ed2,
                                                wlf, w2f, b2e, aggbf);

    // node MLP + residual + LN (MFMA)
    node_kernel<<<NND / 16, 64, 0, stream>>>(xbf, aggbf, w1nf, b1n, w2nf, b2n,
                                             x, gamma, beta, out);
}